// Round 3
// baseline (1365.324 us; speedup 1.0000x reference)
//
#include <hip/hip_runtime.h>

#define BB 16
#define NN 1024
#define HH 1024

__device__ __forceinline__ float wave_reduce_sum(float v) {
#pragma unroll
    for (int off = 32; off > 0; off >>= 1) v += __shfl_down(v, off, 64);
    return v;
}

// ---------------------------------------------------------------------------
// Phase 1: masked row-argmax of gram matrix G = attn * attn^T per (dir, b).
// argmax_j of A == argmax over valid j (opi[j]!=0, j!=i) of dot(attn_i, attn_j)
// (denom is a positive per-row constant; exp is monotone). asp_mask rows that
// are 0 produce zero logits downstream regardless of idx, so ignored here.
// grid = 2 * B * (N/64); block = 256 (16x16), 4x4 micro-tile per thread.
// ---------------------------------------------------------------------------
__global__ __launch_bounds__(256) void gram_argmax_kernel(
    const float* __restrict__ attn0, const float* __restrict__ attn1,
    const int* __restrict__ opi0, const int* __restrict__ opi1,
    int* __restrict__ idx_out)
{
    const int tiles_per_dir = BB * (NN / 64);   // 256
    const int dir = blockIdx.x / tiles_per_dir;
    const int rem = blockIdx.x % tiles_per_dir;
    const int b   = rem >> 4;
    const int it  = rem & 15;
    const int i0  = it << 6;

    const float* __restrict__ base = (dir ? attn1 : attn0) + (size_t)b * NN * HH;
    const int*   __restrict__ opi  = (dir ? opi1 : opi0) + b * NN;

    const int tid = threadIdx.x;
    const int tx = tid & 15, ty = tid >> 4;

    __shared__ float As[64][36];   // [row][k], stride 36 breaks bank aliasing, keeps 16B align
    __shared__ float Bs[32][68];   // [k][col], stride 68 keeps 16B align
    __shared__ float rv[64][16];
    __shared__ int   ri[64][16];

    float bestv[4];
    int   besti[4];
#pragma unroll
    for (int q = 0; q < 4; ++q) { bestv[q] = -3.402823e38f; besti[q] = 0; }

    const int lrow = tid >> 3;   // 0..31
    const int lkq  = tid & 7;    // 0..7

    for (int jt = 0; jt < 16; ++jt) {
        const int j0 = jt << 6;
        float acc[4][4];
#pragma unroll
        for (int q = 0; q < 4; ++q)
#pragma unroll
            for (int p = 0; p < 4; ++p) acc[q][p] = 0.f;

        for (int kc = 0; kc < 32; ++kc) {
            const int k0 = kc << 5;
            __syncthreads();
            {
                const float4 a0 = *(const float4*)(base + (size_t)(i0 + lrow) * HH + k0 + lkq * 4);
                const float4 a1 = *(const float4*)(base + (size_t)(i0 + lrow + 32) * HH + k0 + lkq * 4);
                *(float4*)&As[lrow][lkq * 4]      = a0;
                *(float4*)&As[lrow + 32][lkq * 4] = a1;
                const float4 w0 = *(const float4*)(base + (size_t)(j0 + lrow) * HH + k0 + lkq * 4);
                const float4 w1 = *(const float4*)(base + (size_t)(j0 + lrow + 32) * HH + k0 + lkq * 4);
                Bs[lkq*4+0][lrow] = w0.x; Bs[lkq*4+1][lrow] = w0.y;
                Bs[lkq*4+2][lrow] = w0.z; Bs[lkq*4+3][lrow] = w0.w;
                Bs[lkq*4+0][lrow+32] = w1.x; Bs[lkq*4+1][lrow+32] = w1.y;
                Bs[lkq*4+2][lrow+32] = w1.z; Bs[lkq*4+3][lrow+32] = w1.w;
            }
            __syncthreads();
#pragma unroll
            for (int k4 = 0; k4 < 8; ++k4) {
                const float4 A0 = *(const float4*)&As[ty*4+0][k4*4];
                const float4 A1 = *(const float4*)&As[ty*4+1][k4*4];
                const float4 A2 = *(const float4*)&As[ty*4+2][k4*4];
                const float4 A3 = *(const float4*)&As[ty*4+3][k4*4];
                const float4 B0 = *(const float4*)&Bs[k4*4+0][tx*4];
                const float4 B1 = *(const float4*)&Bs[k4*4+1][tx*4];
                const float4 B2 = *(const float4*)&Bs[k4*4+2][tx*4];
                const float4 B3 = *(const float4*)&Bs[k4*4+3][tx*4];
#define ROWFMA(q, Aq) \
                acc[q][0] = fmaf(Aq.x, B0.x, acc[q][0]); \
                acc[q][0] = fmaf(Aq.y, B1.x, acc[q][0]); \
                acc[q][0] = fmaf(Aq.z, B2.x, acc[q][0]); \
                acc[q][0] = fmaf(Aq.w, B3.x, acc[q][0]); \
                acc[q][1] = fmaf(Aq.x, B0.y, acc[q][1]); \
                acc[q][1] = fmaf(Aq.y, B1.y, acc[q][1]); \
                acc[q][1] = fmaf(Aq.z, B2.y, acc[q][1]); \
                acc[q][1] = fmaf(Aq.w, B3.y, acc[q][1]); \
                acc[q][2] = fmaf(Aq.x, B0.z, acc[q][2]); \
                acc[q][2] = fmaf(Aq.y, B1.z, acc[q][2]); \
                acc[q][2] = fmaf(Aq.z, B2.z, acc[q][2]); \
                acc[q][2] = fmaf(Aq.w, B3.z, acc[q][2]); \
                acc[q][3] = fmaf(Aq.x, B0.w, acc[q][3]); \
                acc[q][3] = fmaf(Aq.y, B1.w, acc[q][3]); \
                acc[q][3] = fmaf(Aq.z, B2.w, acc[q][3]); \
                acc[q][3] = fmaf(Aq.w, B3.w, acc[q][3]);
                ROWFMA(0, A0) ROWFMA(1, A1) ROWFMA(2, A2) ROWFMA(3, A3)
#undef ROWFMA
            }
        }
        // masked running argmax; ascending j scan + strict > keeps first-max
#pragma unroll
        for (int p = 0; p < 4; ++p) {
            const int j = j0 + tx*4 + p;
            const bool jv = (opi[j] != 0);
#pragma unroll
            for (int q = 0; q < 4; ++q) {
                const int i = i0 + ty*4 + q;
                const float v = acc[q][p];
                if (jv && (j != i) && (v > bestv[q])) { bestv[q] = v; besti[q] = j; }
            }
        }
    }
    __syncthreads();
#pragma unroll
    for (int q = 0; q < 4; ++q) { rv[ty*4+q][tx] = bestv[q]; ri[ty*4+q][tx] = besti[q]; }
    __syncthreads();
    if (tid < 64) {
        float bv = rv[tid][0]; int bi = ri[tid][0];
#pragma unroll
        for (int t = 1; t < 16; ++t) {
            const float v = rv[tid][t]; const int ix = ri[tid][t];
            if (v > bv || (v == bv && ix < bi)) { bv = v; bi = ix; }
        }
        idx_out[dir * BB * NN + b * NN + i0 + tid] = bi;
    }
}

// ---------------------------------------------------------------------------
// Phase 2: gather matched opinion row, compute 3 logits per direction
// (concat(asp_h, gathered) @ W + b, masked), combine 0.5*(lA+lO), labels.
// One block per (b,i); 256 threads x 4 h-positions = 1024 = H.
// ---------------------------------------------------------------------------
__global__ __launch_bounds__(256) void logits_kernel(
    const float* __restrict__ a2o_asp, const float* __restrict__ a2o_opi,
    const float* __restrict__ o2a_asp, const float* __restrict__ o2a_opi,
    const int* __restrict__ mA, const int* __restrict__ mO,
    const float* __restrict__ W_A, const float* __restrict__ bias_A,
    const float* __restrict__ W_O, const float* __restrict__ bias_O,
    const int* __restrict__ idx_ws, float* __restrict__ out)
{
    const int row = blockIdx.x;          // b*N + i
    const int b = row >> 10;
    const int tid = threadIdx.x;
    const int idxA = idx_ws[row];
    const int idxO = idx_ws[BB*NN + row];

    const float* aA = a2o_asp + (size_t)row * HH;
    const float* gA = a2o_opi + ((size_t)(b << 10) + idxA) * HH;
    const float* aO = o2a_asp + (size_t)row * HH;
    const float* gO = o2a_opi + ((size_t)(b << 10) + idxO) * HH;

    const int h = tid * 4;
    const float4 va = *(const float4*)(aA + h);
    const float4 vg = *(const float4*)(gA + h);
    const float4 ua = *(const float4*)(aO + h);
    const float4 ug = *(const float4*)(gO + h);

    float acc[6];
#pragma unroll
    for (int c = 0; c < 3; ++c) {
        acc[c] = va.x * W_A[(h+0)*3+c] + va.y * W_A[(h+1)*3+c]
               + va.z * W_A[(h+2)*3+c] + va.w * W_A[(h+3)*3+c]
               + vg.x * W_A[(HH+h+0)*3+c] + vg.y * W_A[(HH+h+1)*3+c]
               + vg.z * W_A[(HH+h+2)*3+c] + vg.w * W_A[(HH+h+3)*3+c];
        acc[3+c] = ua.x * W_O[(h+0)*3+c] + ua.y * W_O[(h+1)*3+c]
                 + ua.z * W_O[(h+2)*3+c] + ua.w * W_O[(h+3)*3+c]
                 + ug.x * W_O[(HH+h+0)*3+c] + ug.y * W_O[(HH+h+1)*3+c]
                 + ug.z * W_O[(HH+h+2)*3+c] + ug.w * W_O[(HH+h+3)*3+c];
    }

    __shared__ float red[4][6];
    const int lane = tid & 63, wv = tid >> 6;
#pragma unroll
    for (int c = 0; c < 6; ++c) {
        const float v = wave_reduce_sum(acc[c]);
        if (lane == 0) red[wv][c] = v;
    }
    __syncthreads();
    if (tid == 0) {
        const int mAv = mA[row], mOv = mO[row];
        float fl[3];
#pragma unroll
        for (int c = 0; c < 3; ++c) {
            const float sA = red[0][c] + red[1][c] + red[2][c] + red[3][c];
            const float sO = red[0][3+c] + red[1][3+c] + red[2][3+c] + red[3][3+c];
            const float lA = mAv ? (sA + bias_A[c]) : 0.f;
            const float lO = mOv ? (sO + bias_O[c]) : 0.f;
            fl[c] = 0.5f * (lA + lO);
            out[BB*NN + row*3 + c] = fl[c];
        }
        int lab = -1;
        if (mAv + mOv > 0) {
            lab = 0;
            if (fl[1] > fl[0]) lab = 1;
            if (fl[2] > fl[lab]) lab = 2;
        }
        out[row] = (float)lab;
    }
}

// ---------------------------------------------------------------------------
// Phase 3: weighted CE over valid rows, mean per sentence, summed over batch.
// Single block; reads final_logits from d_out.
// ---------------------------------------------------------------------------
__global__ __launch_bounds__(256) void loss_kernel(
    const int* __restrict__ mA, const int* __restrict__ mO,
    const int* __restrict__ sent, float* __restrict__ out)
{
    const int tid = threadIdx.x;
    const int lane = tid & 63, wv = tid >> 6;
    __shared__ float rn[4], rd[4];
    float loss = 0.f;
    for (int b = 0; b < BB; ++b) {
        float num = 0.f, den = 0.f;
        for (int i = tid; i < NN; i += 256) {
            const int row = (b << 10) + i;
            const float l0 = out[BB*NN + row*3 + 0];
            const float l1 = out[BB*NN + row*3 + 1];
            const float l2 = out[BB*NN + row*3 + 2];
            const int s = sent[row];
            const bool valid = (mA[row] + mO[row]) > 0;
            const float m = fmaxf(l0, fmaxf(l1, l2));
            const float lse = m + logf(expf(l0 - m) + expf(l1 - m) + expf(l2 - m));
            const float li = (s == 0) ? l0 : ((s == 1) ? l1 : l2);
            const float w = ((s == 0) ? 1.f : ((s == 1) ? 2.f : 4.f)) * (valid ? 1.f : 0.f);
            num += w * (lse - li);
            den += w;
        }
        num = wave_reduce_sum(num);
        den = wave_reduce_sum(den);
        if (lane == 0) { rn[wv] = num; rd[wv] = den; }
        __syncthreads();
        if (tid == 0) {
            const float nn = rn[0] + rn[1] + rn[2] + rn[3];
            const float dd = rd[0] + rd[1] + rd[2] + rd[3];
            loss += (dd > 0.f) ? nn / dd : 0.f;
        }
        __syncthreads();
    }
    if (tid == 0) out[BB*NN + BB*NN*3] = loss;  // out[65536]
}

extern "C" void kernel_launch(void* const* d_in, const int* in_sizes, int n_in,
                              void* d_out, int out_size, void* d_ws, size_t ws_size,
                              hipStream_t stream) {
    const float* a2o_asp = (const float*)d_in[0];
    const float* a2o_opi = (const float*)d_in[1];
    const float* o2a_asp = (const float*)d_in[2];
    const float* o2a_opi = (const float*)d_in[3];
    const int* m_asp_A = (const int*)d_in[4];
    const int* m_opi_A = (const int*)d_in[5];
    const int* m_asp_O = (const int*)d_in[6];
    const int* m_opi_O = (const int*)d_in[7];
    const int* sent    = (const int*)d_in[8];
    const float* W_A = (const float*)d_in[9];
    const float* b_A = (const float*)d_in[10];
    const float* W_O = (const float*)d_in[11];
    const float* b_O = (const float*)d_in[12];
    float* out = (float*)d_out;
    int* idx_ws = (int*)d_ws;   // [2][B][N] int32 = 128 KiB

    // dir0 (A2O) attends with A2O_aspect_h; dir1 (O2A) with O2A_opinion_h
    gram_argmax_kernel<<<512, 256, 0, stream>>>(a2o_asp, o2a_opi, m_opi_A, m_opi_O, idx_ws);
    logits_kernel<<<BB * NN, 256, 0, stream>>>(a2o_asp, a2o_opi, o2a_asp, o2a_opi,
                                               m_asp_A, m_asp_O, W_A, b_A, W_O, b_O,
                                               idx_ws, out);
    loss_kernel<<<1, 256, 0, stream>>>(m_asp_A, m_asp_O, sent, out);
}